// Round 8
// baseline (725.256 us; speedup 1.0000x reference)
//
#include <hip/hip_runtime.h>

typedef _Float16 f16;
typedef __attribute__((ext_vector_type(8))) _Float16 f16x8;
typedef __attribute__((ext_vector_type(4))) float f32x4;

#define TT 4
#define BB 16
#define CC 384

// ---------- LIF step helpers (mirror reference op order, no fma contraction) ----------
__device__ __forceinline__ float lif_soft(float x, float& v) {
  v = __fadd_rn(v, __fmul_rn(__fsub_rn(x, v), 0.5f));
  float s = (__fsub_rn(v, 1.0f) >= 0.0f) ? 1.0f : 0.0f;
  v = __fsub_rn(v, s);
  return s;
}
__device__ __forceinline__ float lif_hard(float x, float& v, float vth) {
  v = __fadd_rn(v, __fmul_rn(__fsub_rn(x, v), 0.5f));
  float s = (__fsub_rn(v, vth) >= 0.0f) ? 1.0f : 0.0f;
  if (s != 0.0f) v = 0.0f;
  return s;
}

// ---------- BN param folding (double precision) ----------
__global__ __launch_bounds__(768) void k_prep(const float* __restrict__ bn1,
                                              const float* __restrict__ bn2,
                                              const float* __restrict__ qkv,
                                              const float* __restrict__ rbn1,
                                              const float* __restrict__ rbn2,
                                              const float* __restrict__ proj,
                                              float* __restrict__ par) {
  int c = threadIdx.x;
  float* s1 = par;          float* o1 = par + 384;
  float* sA = par + 768;    float* oA = par + 1536;
  float* s2 = par + 2304;   float* o2 = par + 2688;
  float* sB = par + 3072;   float* oB = par + 3456;
  if (c < 384) {
    double a = (double)bn1[c] / sqrt((double)bn1[3*384+c] + 1e-5);
    s1[c] = (float)a;
    o1[c] = (float)((double)bn1[384+c] - (double)bn1[2*384+c]*a);
    double a2 = (double)rbn1[c] / sqrt((double)rbn1[3*384+c] + 1e-5);
    s2[c] = (float)a2;
    o2[c] = (float)((double)rbn1[384+c] - (double)rbn1[2*384+c]*a2);
    double a3 = (double)rbn2[c] / sqrt((double)rbn2[3*384+c] + 1e-5);
    double b3 = (double)rbn2[384+c] - (double)rbn2[2*384+c]*a3;
    double a4 = (double)proj[c] / sqrt((double)proj[3*384+c] + 1e-5);
    double b4 = (double)proj[384+c] - (double)proj[2*384+c]*a4;
    sB[c] = (float)(a3*a4);
    oB[c] = (float)(b3*a4 + b4);
  }
  if (c < 768) {
    double a5 = (double)bn2[c] / sqrt((double)bn2[3*768+c] + 1e-5);
    double b5 = (double)bn2[768+c] - (double)bn2[2*768+c]*a5;
    double a6 = (double)qkv[c] / sqrt((double)qkv[3*768+c] + 1e-5);
    double b6 = (double)qkv[768+c] - (double)qkv[2*768+c]*a6;
    sA[c] = (float)(a5*a6);
    oA[c] = (float)(b5*a6 + b6);
  }
}

// ---------- weight split: w = a + 2^-11 * b ----------
__global__ __launch_bounds__(256) void k_wsplit(const float* __restrict__ w,
                                                f16* __restrict__ wa, f16* __restrict__ wb, int n) {
  int i = blockIdx.x * 256 + threadIdx.x;
  if (i < n) {
    float x = w[i];
    f16 a = (f16)x;
    wa[i] = a;
    wb[i] = (f16)((x - (float)a) * 2048.0f);
  }
}

// ---------- input LIF: NCHW fp32 -> NHWC f16 spikes (LDS transpose) ----------
__global__ __launch_bounds__(256) void k_lif_in(const float* __restrict__ x, f16* __restrict__ xs) {
  __shared__ float tile[64][65];   // [c][p]
  const int p0 = blockIdx.x * 64, c0 = blockIdx.y * 64, b = blockIdx.z;
  const int l = threadIdx.x & 63, q = threadIdx.x >> 6;
  float v[16];
  #pragma unroll
  for (int j = 0; j < 16; ++j) v[j] = 0.0f;
  for (int t = 0; t < TT; ++t) {
    __syncthreads();
    #pragma unroll
    for (int j = 0; j < 16; ++j) {
      int ci = q + j*4;
      tile[ci][l] = x[(((size_t)(t*BB + b)*CC + c0 + ci) << 10) + p0 + l];
    }
    __syncthreads();
    #pragma unroll
    for (int j = 0; j < 16; ++j) {
      int pi = q + j*4;
      float s = lif_hard(tile[l][pi], v[j], 1.0f);
      xs[((size_t)(t*BB + b)*1024 + p0 + pi)*CC + c0 + l] = (f16)s;
    }
  }
}

// ---------- staging: global -> LDS, 64B rows, swizzle col ^= ((row>>1)&3)<<4 ----------
// LDS[row][col] = G[row0+row][k0bytes + (col ^ sw(row))]; involution applied again on read.
__device__ __forceinline__ void stage_one(const f16* __restrict__ g, int row0, int k0,
                                          f16* dst, int lane, int i) {
  int loff = i*1024 + lane*16;              // linear byte offset within 8 KB tile
  int row = loff >> 6, col = loff & 63;
  int scol = col ^ (((row >> 1) & 3) << 4); // inverse-swizzled SOURCE column
  const char* src = (const char*)g + (size_t)(row0 + row)*768 + (size_t)(k0*2) + scol;
  __builtin_amdgcn_global_load_lds((const __attribute__((address_space(1))) void*)src,
                                   (__attribute__((address_space(3))) void*)((char*)dst + i*1024),
                                   16, 0, 0);
}

// fragment read with matching swizzle (row in [0,128), fq selects 16B k-slot)
__device__ __forceinline__ f16x8 fragld32(const f16* arr, int row, int fq) {
  int off = row*64 + ((fq*16) ^ (((row >> 1) & 3) << 4));
  return *(const f16x8*)((const char*)arr + off);
}

// ---------- split-f16 MFMA GEMM, counted-vmcnt double-buffered pipeline (BK=32) ----------
// out[m][o] = bn( sum_c X[m][c]*W[o][c] );  X = X1 + 2^-11 X2 (NP==3) or exact X1 (NP==2).
// XCD-chunked block swizzle (bijective, nwg%8==0). Per-iter ledger:
//   stage(it+1) [2L in flight] -> s_waitcnt vmcnt(L) [stage(it) landed] -> s_barrier
//   -> compute(it) -> s_barrier [readers done before stage(it+2) overwrites].
template<int NP>
__global__ __launch_bounds__(256, 2) void k_gemm(const f16* __restrict__ X1, const f16* __restrict__ X2,
    const f16* __restrict__ Wa, const f16* __restrict__ Wb,
    const float* __restrict__ scale, const float* __restrict__ bias,
    float* __restrict__ out0, float* __restrict__ out1) {
  constexpr int ARR = (NP == 3) ? 4 : 3;            // tiles per buffer
  __shared__ __align__(16) f16 lds[2*ARR*4096];     // 8 KB per tile (128 rows x 64 B)
  const int gx = gridDim.x;
  const int bid = blockIdx.y * gx + blockIdx.x;
  const int chunk = (gx * gridDim.y) >> 3;          // nwg % 8 == 0 for all our grids
  const int nb = (bid & 7) * chunk + (bid >> 3);    // chunked per-XCD, x fastest inside
  const int m0 = (nb / gx) * 128;
  const int o0 = (nb % gx) * 128;
  const int lane = threadIdx.x & 63, wid = threadIdx.x >> 6;
  const int wr = wid >> 1, wc = wid & 1;
  const int fr = lane & 15, fq = lane >> 4;
  f32x4 acc_h[4][4], acc_l[4][4];
  #pragma unroll
  for (int i = 0; i < 4; ++i)
    #pragma unroll
    for (int j = 0; j < 4; ++j) { acc_h[i][j] = (f32x4){0,0,0,0}; acc_l[i][j] = (f32x4){0,0,0,0}; }

  // NP==3: 4 arrays x 8 insts, one array per wave -> L=8 per wave.
  // NP==2: 3 arrays x 8 insts = 24 slots flat -> 6 per wave -> L=6.
  auto stage_all = [&](int buf, int k0) {
    f16* base = lds + buf*(ARR*4096);
    if (NP == 3) {
      const f16* g = (wid == 0) ? X1 : (wid == 1) ? X2 : (wid == 2) ? Wa : Wb;
      int row0 = (wid <= 1) ? m0 : o0;
      f16* dst = base + wid*4096;
      #pragma unroll
      for (int i = 0; i < 8; ++i) stage_one(g, row0, k0, dst, lane, i);
    } else {
      #pragma unroll
      for (int j = 0; j < 6; ++j) {
        int s = wid*6 + j;
        int arr = s >> 3, inst = s & 7;
        const f16* g = (arr == 0) ? X1 : (arr == 1) ? Wa : Wb;
        int row0 = (arr == 0) ? m0 : o0;
        stage_one(g, row0, k0, base + arr*4096, lane, inst);
      }
    }
  };

  // prologue: stage K-tile 0 into buf 0
  stage_all(0, 0);

  for (int it = 0; it < 12; ++it) {                 // K = 384 = 12 x 32
    const int cur = it & 1;
    if (it < 11) stage_all(cur ^ 1, (it + 1)*32);   // issue next tile (stays in flight)
    if (it < 11) {
      if constexpr (NP == 3) asm volatile("s_waitcnt vmcnt(8)" ::: "memory");
      else                   asm volatile("s_waitcnt vmcnt(6)" ::: "memory");
    } else {
      asm volatile("s_waitcnt vmcnt(0)" ::: "memory");
    }
    __builtin_amdgcn_sched_barrier(0);
    __builtin_amdgcn_s_barrier();                   // all waves' stage(it) landed
    const f16* bX1 = lds + cur*(ARR*4096);
    const f16* bW1 = (NP == 3) ? bX1 + 2*4096 : bX1 + 4096;
    const f16* bW2 = (NP == 3) ? bX1 + 3*4096 : bX1 + 2*4096;
    f16x8 a1[4], b1[4], b2[4];
    #pragma unroll
    for (int mi = 0; mi < 4; ++mi) a1[mi] = fragld32(bX1, wr*64 + mi*16 + fr, fq);
    #pragma unroll
    for (int oi = 0; oi < 4; ++oi) {
      b1[oi] = fragld32(bW1, wc*64 + oi*16 + fr, fq);
      b2[oi] = fragld32(bW2, wc*64 + oi*16 + fr, fq);
    }
    if (NP == 3) {
      const f16* bX2 = bX1 + 4096;
      f16x8 a2[4];
      #pragma unroll
      for (int mi = 0; mi < 4; ++mi) a2[mi] = fragld32(bX2, wr*64 + mi*16 + fr, fq);
      #pragma unroll
      for (int mi = 0; mi < 4; ++mi)
        #pragma unroll
        for (int oi = 0; oi < 4; ++oi) {
          acc_h[mi][oi] = __builtin_amdgcn_mfma_f32_16x16x32_f16(a1[mi], b1[oi], acc_h[mi][oi], 0, 0, 0);
          acc_l[mi][oi] = __builtin_amdgcn_mfma_f32_16x16x32_f16(a1[mi], b2[oi], acc_l[mi][oi], 0, 0, 0);
          acc_l[mi][oi] = __builtin_amdgcn_mfma_f32_16x16x32_f16(a2[mi], b1[oi], acc_l[mi][oi], 0, 0, 0);
        }
    } else {
      #pragma unroll
      for (int mi = 0; mi < 4; ++mi)
        #pragma unroll
        for (int oi = 0; oi < 4; ++oi) {
          acc_h[mi][oi] = __builtin_amdgcn_mfma_f32_16x16x32_f16(a1[mi], b1[oi], acc_h[mi][oi], 0, 0, 0);
          acc_l[mi][oi] = __builtin_amdgcn_mfma_f32_16x16x32_f16(a1[mi], b2[oi], acc_l[mi][oi], 0, 0, 0);
        }
    }
    __builtin_amdgcn_s_barrier();                   // readers done -> buffer reusable
  }

  #pragma unroll
  for (int oi = 0; oi < 4; ++oi) {
    int o = o0 + wc*64 + oi*16 + fr;
    float sc = scale[o], bi = bias[o];
    float* op = out0; int oc = o;
    if (o >= 384) { op = out1; oc = o - 384; }
    #pragma unroll
    for (int mi = 0; mi < 4; ++mi) {
      f32x4 h = acc_h[mi][oi], lo2 = acc_l[mi][oi];
      #pragma unroll
      for (int r = 0; r < 4; ++r) {
        int m = m0 + wr*64 + mi*16 + fq*4 + r;
        float y = fmaf(0.00048828125f, lo2[r], h[r]);   // + 2^-11 * low
        op[(size_t)m*384 + oc] = fmaf(y, sc, bi);
      }
    }
  }
}

// ---------- depthwise 3x3, NHWC, fp32 in -> split-f16 pair out, virtual pad pv[c] ----------
__global__ __launch_bounds__(256) void k_dw(const float* __restrict__ in, const float* __restrict__ wd,
                                            const float* __restrict__ pv,
                                            f16* __restrict__ outA, f16* __restrict__ outB) {
  const int ct = blockIdx.x, h = blockIdx.y, n = blockIdx.z;
  const int c = ct*64 + (threadIdx.x & 63);
  const int wq = threadIdx.x >> 6;
  float w9[9];
  #pragma unroll
  for (int i = 0; i < 9; ++i) w9[i] = wd[c*9 + i];
  const float pvc = pv[c];
  const float* base = in + (size_t)n*1024*CC;
  for (int wi = 0; wi < 8; ++wi) {
    int w = wq*8 + wi;
    float acc = 0.0f;
    #pragma unroll
    for (int dh = -1; dh <= 1; ++dh)
      #pragma unroll
      for (int dw = -1; dw <= 1; ++dw) {
        int hh = h + dh, ww = w + dw;
        float vv = ((unsigned)hh < 32u && (unsigned)ww < 32u) ? base[(size_t)(hh*32 + ww)*CC + c] : pvc;
        acc = fmaf(w9[(dh+1)*3 + dw + 1], vv, acc);
      }
    f16 a = (f16)acc;
    size_t off = ((size_t)n*1024 + h*32 + w)*CC + c;
    outA[off] = a;
    outB[off] = (f16)((acc - (float)a) * 2048.0f);
  }
}

// ---------- qk path stage 1: LIF(soft) + spatial partial sums ----------
__global__ __launch_bounds__(256) void k_qksum(const float* __restrict__ y6qk, float* __restrict__ partial) {
  __shared__ float red[4][4][64];
  const int ps = blockIdx.x, ct = blockIdx.y, b = blockIdx.z;
  const int l = threadIdx.x & 63, pg = threadIdx.x >> 6;
  const int c = ct*64 + l;
  float sums[4] = {0,0,0,0};
  for (int i = 0; i < 32; ++i) {
    int p = ps*128 + pg*32 + i;
    float v = 0.0f;
    #pragma unroll
    for (int t = 0; t < TT; ++t) {
      float xv = y6qk[((size_t)(t*BB + b)*1024 + p)*CC + c];
      sums[t] += lif_soft(xv, v);
    }
  }
  #pragma unroll
  for (int t = 0; t < TT; ++t) red[pg][t][l] = sums[t];
  __syncthreads();
  int t2 = threadIdx.x >> 6;
  float tot = red[0][t2][l] + red[1][t2][l] + red[2][t2][l] + red[3][t2][l];
  partial[(((size_t)ps*4 + t2)*BB + b)*CC + c] = tot;
}

// ---------- qk path stage 2: combine slices + LIF(hard 0.5) -> gate ----------
__global__ __launch_bounds__(256) void k_gate(const float* __restrict__ partial, float* __restrict__ gate) {
  int g = blockIdx.x*256 + threadIdx.x;   // 6144 = 16*384
  int b = g / CC, c = g % CC;
  float sums[4];
  #pragma unroll
  for (int t = 0; t < TT; ++t) {
    float s = 0.0f;
    for (int ps = 0; ps < 8; ++ps) s += partial[(((size_t)ps*4 + t)*BB + b)*CC + c];
    sums[t] = s;
  }
  float v = 0.0f;
  #pragma unroll
  for (int t = 0; t < TT; ++t)
    gate[(size_t)(t*BB + b)*CC + c] = lif_hard(sums[t], v, 0.5f);
}

// ---------- v path: LIF(soft) * gate -> att (exact f16 0/1) ----------
__global__ __launch_bounds__(256) void k_vatt(const float* __restrict__ y6v, const float* __restrict__ gate,
                                              f16* __restrict__ att) {
  const int psl = blockIdx.x, ct = blockIdx.y, b = blockIdx.z;
  const int l = threadIdx.x & 63, pg = threadIdx.x >> 6;
  const int c = ct*64 + l;
  float g4[4];
  #pragma unroll
  for (int t = 0; t < TT; ++t) g4[t] = gate[(size_t)(t*BB + b)*CC + c];
  for (int i = 0; i < 16; ++i) {
    int p = psl*64 + pg*16 + i;
    float v = 0.0f;
    #pragma unroll
    for (int t = 0; t < TT; ++t) {
      size_t off = ((size_t)(t*BB + b)*1024 + p)*CC + c;
      float s = lif_soft(y6v[off], v);
      att[off] = (f16)(s * g4[t]);
    }
  }
}

// ---------- output LIF: NHWC fp32 -> NCHW fp32, soft LIF * scale (LDS transpose) ----------
__global__ __launch_bounds__(256) void k_lif_out(const float* __restrict__ z, const float* __restrict__ scalep,
                                                 float* __restrict__ out) {
  __shared__ float tile[64][65];  // [p][c]
  const int p0 = blockIdx.x * 64, c0 = blockIdx.y * 64, b = blockIdx.z;
  const int l = threadIdx.x & 63, q = threadIdx.x >> 6;
  const float sc = scalep[0];
  float v[16];
  #pragma unroll
  for (int j = 0; j < 16; ++j) v[j] = 0.0f;
  for (int t = 0; t < TT; ++t) {
    __syncthreads();
    #pragma unroll
    for (int j = 0; j < 16; ++j) {
      int pi = q + j*4;
      tile[pi][l] = z[((size_t)(t*BB + b)*1024 + p0 + pi)*CC + c0 + l];
    }
    __syncthreads();
    #pragma unroll
    for (int j = 0; j < 16; ++j) {
      int ci = q + j*4;
      float s = lif_soft(tile[l][ci], v[j]) * sc;
      out[(((size_t)(t*BB + b))*CC + c0 + ci)*1024 + p0 + l] = s;
    }
  }
}

extern "C" void kernel_launch(void* const* d_in, const int* in_sizes, int n_in,
                              void* d_out, int out_size, void* d_ws, size_t ws_size,
                              hipStream_t stream) {
  const float* x      = (const float*)d_in[0];
  const float* r1_w1  = (const float*)d_in[1];
  const float* r1_bn1 = (const float*)d_in[2];
  const float* r1_dw  = (const float*)d_in[3];
  const float* r1_pw  = (const float*)d_in[4];
  const float* r1_bn2 = (const float*)d_in[5];
  const float* qkv_bn = (const float*)d_in[6];
  const float* r2_w1  = (const float*)d_in[7];
  const float* r2_bn1 = (const float*)d_in[8];
  const float* r2_dw  = (const float*)d_in[9];
  const float* r2_pw  = (const float*)d_in[10];
  const float* r2_bn2 = (const float*)d_in[11];
  const float* proj_bn= (const float*)d_in[12];
  const float* scale  = (const float*)d_in[13];

  float* ws = (float*)d_ws;
  const size_t SEG = 12582912;              // 48 MB in floats
  float* W0f = ws;
  float* W1  = ws + SEG;
  float* W2f = ws + 3*SEG;
  float* W3  = ws + 4*SEG;
  f16* xs   = (f16*)W0f;                    // spikes -> p1a -> p2b
  f16* p1a  = (f16*)W0f;
  f16* p2b  = (f16*)W0f;
  f16* p1b  = (f16*)W2f;                    // -> att -> p2a
  f16* att  = (f16*)W2f;
  f16* p2a  = (f16*)W2f;
  float* t1   = W1;                         // gemm1 out -> y6qk -> t2
  float* y6qk = W1;
  float* t2   = W1;
  float* y6v  = W3;                         // -> z
  float* z    = W3;

  f16* wsp = (f16*)(ws + 6*SEG);            // shared region (phases A/B/C)
  f16* w1a = wsp,            *w1b = wsp + 147456;
  f16* pwa = wsp + 294912,   *pwb = wsp + 589824;        // phase A (r1)
  float* partial = (float*)wsp;                          // phase B: 196608 floats
  float* gate    = (float*)wsp + 196608;                 //          +24576
  f16* q1a = wsp,            *q1b = wsp + 147456;        // phase C (r2)
  f16* qpa = wsp + 294912,   *qpb = wsp + 442368;

  float* par = ws + 6*SEG + 442368;         // 3840 floats of BN params
  float* s1 = par,        *o1 = par + 384;
  float* sA = par + 768,  *oA = par + 1536;
  float* s2 = par + 2304, *o2 = par + 2688;
  float* sB = par + 3072, *oB = par + 3456;

  k_prep<<<1, 768, 0, stream>>>(r1_bn1, r1_bn2, qkv_bn, r2_bn1, r2_bn2, proj_bn, par);
  k_wsplit<<<576, 256, 0, stream>>>(r1_w1, w1a, w1b, 147456);
  k_wsplit<<<1152, 256, 0, stream>>>(r1_pw, pwa, pwb, 294912);
  k_lif_in<<<dim3(16, 6, 16), 256, 0, stream>>>(x, xs);
  // repconv1
  k_gemm<2><<<dim3(3, 512), 256, 0, stream>>>(xs, (const f16*)nullptr, w1a, w1b, s1, o1, t1, t1);
  k_dw<<<dim3(6, 32, 64), 256, 0, stream>>>(t1, r1_dw, o1, p1a, p1b);
  k_gemm<3><<<dim3(6, 512), 256, 0, stream>>>(p1a, p1b, pwa, pwb, sA, oA, y6qk, y6v);
  // spike attention gating
  k_qksum<<<dim3(8, 6, 16), 256, 0, stream>>>(y6qk, partial);
  k_gate<<<24, 256, 0, stream>>>(partial, gate);
  k_vatt<<<dim3(16, 6, 16), 256, 0, stream>>>(y6v, gate, att);
  // repconv2 (re-split r2 weights into the shared region after gate consumed)
  k_wsplit<<<576, 256, 0, stream>>>(r2_w1, q1a, q1b, 147456);
  k_wsplit<<<576, 256, 0, stream>>>(r2_pw, qpa, qpb, 147456);
  k_gemm<2><<<dim3(3, 512), 256, 0, stream>>>(att, (const f16*)nullptr, q1a, q1b, s2, o2, t2, t2);
  k_dw<<<dim3(6, 32, 64), 256, 0, stream>>>(t2, r2_dw, o2, p2a, p2b);
  k_gemm<3><<<dim3(3, 512), 256, 0, stream>>>(p2a, p2b, qpa, qpb, sB, oB, z, z);
  // output LIF * scale (NHWC -> NCHW)
  k_lif_out<<<dim3(16, 6, 16), 256, 0, stream>>>(z, scale, (float*)d_out);
}

// Round 9
// 544.274 us; speedup vs baseline: 1.3325x; 1.3325x over previous
//
#include <hip/hip_runtime.h>

typedef _Float16 f16;
typedef __attribute__((ext_vector_type(8))) _Float16 f16x8;
typedef __attribute__((ext_vector_type(4))) float f32x4;

#define TT 4
#define BB 16
#define CC 384

// ---------- LIF step helpers (mirror reference op order, no fma contraction) ----------
__device__ __forceinline__ float lif_soft(float x, float& v) {
  v = __fadd_rn(v, __fmul_rn(__fsub_rn(x, v), 0.5f));
  float s = (__fsub_rn(v, 1.0f) >= 0.0f) ? 1.0f : 0.0f;
  v = __fsub_rn(v, s);
  return s;
}
__device__ __forceinline__ float lif_hard(float x, float& v, float vth) {
  v = __fadd_rn(v, __fmul_rn(__fsub_rn(x, v), 0.5f));
  float s = (__fsub_rn(v, vth) >= 0.0f) ? 1.0f : 0.0f;
  if (s != 0.0f) v = 0.0f;
  return s;
}

// ---------- BN param folding (double precision) ----------
__global__ __launch_bounds__(768) void k_prep(const float* __restrict__ bn1,
                                              const float* __restrict__ bn2,
                                              const float* __restrict__ qkv,
                                              const float* __restrict__ rbn1,
                                              const float* __restrict__ rbn2,
                                              const float* __restrict__ proj,
                                              float* __restrict__ par) {
  int c = threadIdx.x;
  float* s1 = par;          float* o1 = par + 384;
  float* sA = par + 768;    float* oA = par + 1536;
  float* s2 = par + 2304;   float* o2 = par + 2688;
  float* sB = par + 3072;   float* oB = par + 3456;
  if (c < 384) {
    double a = (double)bn1[c] / sqrt((double)bn1[3*384+c] + 1e-5);
    s1[c] = (float)a;
    o1[c] = (float)((double)bn1[384+c] - (double)bn1[2*384+c]*a);
    double a2 = (double)rbn1[c] / sqrt((double)rbn1[3*384+c] + 1e-5);
    s2[c] = (float)a2;
    o2[c] = (float)((double)rbn1[384+c] - (double)rbn1[2*384+c]*a2);
    double a3 = (double)rbn2[c] / sqrt((double)rbn2[3*384+c] + 1e-5);
    double b3 = (double)rbn2[384+c] - (double)rbn2[2*384+c]*a3;
    double a4 = (double)proj[c] / sqrt((double)proj[3*384+c] + 1e-5);
    double b4 = (double)proj[384+c] - (double)proj[2*384+c]*a4;
    sB[c] = (float)(a3*a4);
    oB[c] = (float)(b3*a4 + b4);
  }
  if (c < 768) {
    double a5 = (double)bn2[c] / sqrt((double)bn2[3*768+c] + 1e-5);
    double b5 = (double)bn2[768+c] - (double)bn2[2*768+c]*a5;
    double a6 = (double)qkv[c] / sqrt((double)qkv[3*768+c] + 1e-5);
    double b6 = (double)qkv[768+c] - (double)qkv[2*768+c]*a6;
    sA[c] = (float)(a5*a6);
    oA[c] = (float)(b5*a6 + b6);
  }
}

// ---------- weight split: w = a + 2^-11 * b ----------
__global__ __launch_bounds__(256) void k_wsplit(const float* __restrict__ w,
                                                f16* __restrict__ wa, f16* __restrict__ wb, int n) {
  int i = blockIdx.x * 256 + threadIdx.x;
  if (i < n) {
    float x = w[i];
    f16 a = (f16)x;
    wa[i] = a;
    wb[i] = (f16)((x - (float)a) * 2048.0f);
  }
}

// ---------- input LIF: NCHW fp32 -> NHWC f16 spikes (LDS transpose) ----------
__global__ __launch_bounds__(256) void k_lif_in(const float* __restrict__ x, f16* __restrict__ xs) {
  __shared__ float tile[64][65];   // [c][p]
  const int p0 = blockIdx.x * 64, c0 = blockIdx.y * 64, b = blockIdx.z;
  const int l = threadIdx.x & 63, q = threadIdx.x >> 6;
  float v[16];
  #pragma unroll
  for (int j = 0; j < 16; ++j) v[j] = 0.0f;
  for (int t = 0; t < TT; ++t) {
    __syncthreads();
    #pragma unroll
    for (int j = 0; j < 16; ++j) {
      int ci = q + j*4;
      tile[ci][l] = x[(((size_t)(t*BB + b)*CC + c0 + ci) << 10) + p0 + l];
    }
    __syncthreads();
    #pragma unroll
    for (int j = 0; j < 16; ++j) {
      int pi = q + j*4;
      float s = lif_hard(tile[l][pi], v[j], 1.0f);
      xs[((size_t)(t*BB + b)*1024 + p0 + pi)*CC + c0 + l] = (f16)s;
    }
  }
}

// ---------- staging: global -> LDS, 64B rows, swizzle col ^= ((row>>1)&3)<<4 ----------
// EPI==1 X-side uses t-grouped rows: gm = t*16384 + b*1024 + p0 + (row&31), t = row>>5.
template<int EPI>
__device__ __forceinline__ void stage_arrT(const f16* __restrict__ g, int m0, int b_, int p0,
                                           int k0, f16* dst, int lane, int i0, int i1, bool isX) {
  #pragma unroll
  for (int i = i0; i < i1; ++i) {
    int loff = i*1024 + lane*16;              // linear byte offset within 8 KB tile
    int row = loff >> 6, col = loff & 63;
    int scol = col ^ (((row >> 1) & 3) << 4); // inverse-swizzled SOURCE column
    int gm;
    if (EPI == 1 && isX) gm = ((row >> 5) << 14) + (b_ << 10) + p0 + (row & 31);
    else                 gm = m0 + row;
    const char* src = (const char*)g + (size_t)gm*768 + (size_t)(k0*2) + scol;
    __builtin_amdgcn_global_load_lds((const __attribute__((address_space(1))) void*)src,
                                     (__attribute__((address_space(3))) void*)((char*)dst + i*1024),
                                     16, 0, 0);
  }
}

// fragment read with matching swizzle (row in [0,128), fq selects 16B k-slot)
__device__ __forceinline__ f16x8 fragld32(const f16* arr, int row, int fq) {
  int off = row*64 + ((fq*16) ^ (((row >> 1) & 3) << 4));
  return *(const f16x8*)((const char*)arr + off);
}

// ---------- split-f16 MFMA GEMM, 2-phase double-buffered (BK=32), XCD-chunked ----------
// NP: 2 or 3 MFMA passes. EPI: 0 = plain BN store; 1 = qkv fused epilogue (t-grouped
// blocks, in-LDS transpose, LIF over t; qk-half -> partial spike sums, v-half -> spikes).
// GATE: multiply A-frags by per-(tb,c) f16 gate (exact 0/1).
template<int NP, int EPI, int GATE>
__global__ __launch_bounds__(256, 2) void k_gemm(const f16* __restrict__ X1, const f16* __restrict__ X2,
    const f16* __restrict__ Wa, const f16* __restrict__ Wb,
    const float* __restrict__ scale, const float* __restrict__ bias,
    float* __restrict__ out0, float* __restrict__ out1,
    const f16* __restrict__ gatep, f16* __restrict__ sOut, f16* __restrict__ part) {
  constexpr int ARR = (NP == 3) ? 4 : 3;            // tiles per buffer
  __shared__ __align__(16) f16 lds[2*ARR*4096];     // 8 KB per tile (128 rows x 64 B)
  const int gx = gridDim.x;
  const int bid = blockIdx.y * gx + blockIdx.x;
  const int chunk = (gx * gridDim.y) >> 3;          // nwg % 8 == 0 for all our grids
  const int nb = (bid & 7) * chunk + (bid >> 3);    // chunked per-XCD, x fastest inside
  const int o0 = (nb % gx) * 128;
  const int mb = nb / gx;
  const int m0 = mb * 128;                          // EPI==0 row base
  const int b_ = mb >> 5, p0 = (mb & 31) << 5;      // EPI==1 decode (b, p-slice)
  const int lane = threadIdx.x & 63, wid = threadIdx.x >> 6;
  const int wr = wid >> 1, wc = wid & 1;
  const int fr = lane & 15, fq = lane >> 4;
  f32x4 acc_h[4][4], acc_l[4][4];
  #pragma unroll
  for (int i = 0; i < 4; ++i)
    #pragma unroll
    for (int j = 0; j < 4; ++j) { acc_h[i][j] = (f32x4){0,0,0,0}; acc_l[i][j] = (f32x4){0,0,0,0}; }

  auto stage_all = [&](int buf, int k0) {
    f16* base = lds + buf*(ARR*4096);
    if (NP == 3) {
      if (wid == 0)      stage_arrT<EPI>(X1, m0, b_, p0, k0, base,          lane, 0, 8, true);
      else if (wid == 1) stage_arrT<EPI>(X2, m0, b_, p0, k0, base + 4096,   lane, 0, 8, true);
      else if (wid == 2) stage_arrT<EPI>(Wa, o0, b_, p0, k0, base + 2*4096, lane, 0, 8, false);
      else               stage_arrT<EPI>(Wb, o0, b_, p0, k0, base + 3*4096, lane, 0, 8, false);
    } else {
      if (wid == 0)      stage_arrT<EPI>(X1, m0, b_, p0, k0, base,          lane, 0, 4, true);
      else if (wid == 1) stage_arrT<EPI>(X1, m0, b_, p0, k0, base,          lane, 4, 8, true);
      else if (wid == 2) stage_arrT<EPI>(Wa, o0, b_, p0, k0, base + 4096,   lane, 0, 8, false);
      else               stage_arrT<EPI>(Wb, o0, b_, p0, k0, base + 2*4096, lane, 0, 8, false);
    }
  };

  // gate prefetch (GATE only): 16B of gate row for this block's (t,b), k-slot fq
  const char* gbase = nullptr;
  f16x8 g8{}, gn{};
  if constexpr (GATE) {
    gbase = (const char*)gatep + (size_t)(m0 >> 10)*768 + fq*16;
    g8 = *(const f16x8*)gbase;
  }

  // prologue: stage K-tile 0 into buf 0 (syncthreads drains vmcnt+lgkmcnt)
  stage_all(0, 0);
  __syncthreads();

  for (int it = 0; it < 12; ++it) {                 // K = 384 = 12 x 32
    const int cur = it & 1;
    if (it < 11) stage_all(cur ^ 1, (it + 1)*32);   // issue next tile FIRST (hides HBM latency)
    if constexpr (GATE) { if (it < 11) gn = *(const f16x8*)(gbase + (it + 1)*64); }
    const f16* bX1 = lds + cur*(ARR*4096);
    const f16* bW1 = (NP == 3) ? bX1 + 2*4096 : bX1 + 4096;
    const f16* bW2 = (NP == 3) ? bX1 + 3*4096 : bX1 + 2*4096;
    f16x8 a1[4], b1[4], b2[4];
    #pragma unroll
    for (int mi = 0; mi < 4; ++mi) a1[mi] = fragld32(bX1, wr*64 + mi*16 + fr, fq);
    if constexpr (GATE) {
      #pragma unroll
      for (int mi = 0; mi < 4; ++mi) a1[mi] = a1[mi] * g8;   // exact 0/1 * 0/1
    }
    #pragma unroll
    for (int oi = 0; oi < 4; ++oi) {
      b1[oi] = fragld32(bW1, wc*64 + oi*16 + fr, fq);
      b2[oi] = fragld32(bW2, wc*64 + oi*16 + fr, fq);
    }
    if (NP == 3) {
      const f16* bX2 = bX1 + 4096;
      f16x8 a2[4];
      #pragma unroll
      for (int mi = 0; mi < 4; ++mi) a2[mi] = fragld32(bX2, wr*64 + mi*16 + fr, fq);
      #pragma unroll
      for (int mi = 0; mi < 4; ++mi)
        #pragma unroll
        for (int oi = 0; oi < 4; ++oi) {
          acc_h[mi][oi] = __builtin_amdgcn_mfma_f32_16x16x32_f16(a1[mi], b1[oi], acc_h[mi][oi], 0, 0, 0);
          acc_l[mi][oi] = __builtin_amdgcn_mfma_f32_16x16x32_f16(a1[mi], b2[oi], acc_l[mi][oi], 0, 0, 0);
          acc_l[mi][oi] = __builtin_amdgcn_mfma_f32_16x16x32_f16(a2[mi], b1[oi], acc_l[mi][oi], 0, 0, 0);
        }
    } else {
      #pragma unroll
      for (int mi = 0; mi < 4; ++mi)
        #pragma unroll
        for (int oi = 0; oi < 4; ++oi) {
          acc_h[mi][oi] = __builtin_amdgcn_mfma_f32_16x16x32_f16(a1[mi], b1[oi], acc_h[mi][oi], 0, 0, 0);
          acc_l[mi][oi] = __builtin_amdgcn_mfma_f32_16x16x32_f16(a1[mi], b2[oi], acc_l[mi][oi], 0, 0, 0);
        }
    }
    __syncthreads();   // drains this wave's stage loads (vmcnt) + releases buf for overwrite
    if constexpr (GATE) { if (it < 11) g8 = gn; }
  }

  if constexpr (EPI == 0) {
    #pragma unroll
    for (int oi = 0; oi < 4; ++oi) {
      int o = o0 + wc*64 + oi*16 + fr;
      float sc = scale[o], bi = bias[o];
      float* op = out0; int oc = o;
      if (o >= 384) { op = out1; oc = o - 384; }
      #pragma unroll
      for (int mi = 0; mi < 4; ++mi) {
        f32x4 h = acc_h[mi][oi], lo2 = acc_l[mi][oi];
        #pragma unroll
        for (int r = 0; r < 4; ++r) {
          int m = m0 + wr*64 + mi*16 + fq*4 + r;
          float y = fmaf(0.00048828125f, lo2[r], h[r]);   // + 2^-11 * low
          op[(size_t)m*384 + oc] = fmaf(y, sc, bi);
        }
      }
    }
  } else {
    // fused qkv epilogue: BN -> in-LDS transpose -> LIF over t (rows = 4t x 32p)
    float* T = (float*)lds;  // 128 x 128 fp32 = 64 KB (staging reads done: loop-final barrier)
    #pragma unroll
    for (int oi = 0; oi < 4; ++oi) {
      int ol = wc*64 + oi*16 + fr;
      float sc = scale[o0 + ol], bi = bias[o0 + ol];
      #pragma unroll
      for (int mi = 0; mi < 4; ++mi) {
        f32x4 h = acc_h[mi][oi], lo2 = acc_l[mi][oi];
        #pragma unroll
        for (int r = 0; r < 4; ++r) {
          int R = wr*64 + mi*16 + fq*4 + r;
          float y = fmaf(0.00048828125f, lo2[r], h[r]);
          T[R*128 + ol] = fmaf(y, sc, bi);
        }
      }
    }
    __syncthreads();
    const int tid = threadIdx.x;
    const int oc = tid & 127, ph = tid >> 7;
    if (o0 >= 384) {
      // v-half: spikes (exact 0/1) -> sOut[(t*16+b)*1024+p0+p][o0-384+oc]
      const int ocg = (o0 - 384) + oc;
      #pragma unroll
      for (int i = 0; i < 16; ++i) {
        int p = ph*16 + i;
        float v = 0.0f;
        #pragma unroll
        for (int t = 0; t < TT; ++t) {
          float s = lif_soft(T[(t*32 + p)*128 + oc], v);
          sOut[((size_t)((t*16 + b_)*1024 + p0 + p))*384 + ocg] = (f16)s;
        }
      }
    } else {
      // qk-half: spike sums over this thread's 16 p (integer, f16-exact)
      float ps4[4] = {0,0,0,0};
      for (int i = 0; i < 16; ++i) {
        int p = ph*16 + i;
        float v = 0.0f;
        #pragma unroll
        for (int t = 0; t < TT; ++t) ps4[t] += lif_soft(T[(t*32 + p)*128 + oc], v);
      }
      int slice = (p0 >> 4) + ph;   // 64 half-slices of 16 p
      #pragma unroll
      for (int t = 0; t < TT; ++t)
        part[(((size_t)slice*4 + t)*16 + b_)*384 + o0 + oc] = (f16)ps4[t];
    }
  }
}

// ---------- depthwise 3x3, NHWC, fp32 in -> split-f16 pair out, virtual pad pv[c] ----------
__global__ __launch_bounds__(256) void k_dw(const float* __restrict__ in, const float* __restrict__ wd,
                                            const float* __restrict__ pv,
                                            f16* __restrict__ outA, f16* __restrict__ outB) {
  const int ct = blockIdx.x, h = blockIdx.y, n = blockIdx.z;
  const int c = ct*64 + (threadIdx.x & 63);
  const int wq = threadIdx.x >> 6;
  float w9[9];
  #pragma unroll
  for (int i = 0; i < 9; ++i) w9[i] = wd[c*9 + i];
  const float pvc = pv[c];
  const float* base = in + (size_t)n*1024*CC;
  for (int wi = 0; wi < 8; ++wi) {
    int w = wq*8 + wi;
    float acc = 0.0f;
    #pragma unroll
    for (int dh = -1; dh <= 1; ++dh)
      #pragma unroll
      for (int dw = -1; dw <= 1; ++dw) {
        int hh = h + dh, ww = w + dw;
        float vv = ((unsigned)hh < 32u && (unsigned)ww < 32u) ? base[(size_t)(hh*32 + ww)*CC + c] : pvc;
        acc = fmaf(w9[(dh+1)*3 + dw + 1], vv, acc);
      }
    f16 a = (f16)acc;
    size_t off = ((size_t)n*1024 + h*32 + w)*CC + c;
    outA[off] = a;
    outB[off] = (f16)((acc - (float)a) * 2048.0f);
  }
}

// ---------- gate: combine 64 partial half-slices + LIF(hard 0.5) -> f16 gate ----------
__global__ __launch_bounds__(256) void k_gate(const f16* __restrict__ partial, f16* __restrict__ gate16) {
  int g = blockIdx.x*256 + threadIdx.x;   // 6144 = 16*384
  int b = g / CC, c = g % CC;
  float sums[4];
  #pragma unroll
  for (int t = 0; t < TT; ++t) {
    float s = 0.0f;
    for (int ps = 0; ps < 64; ++ps) s += (float)partial[(((size_t)ps*4 + t)*BB + b)*CC + c];
    sums[t] = s;
  }
  float v = 0.0f;
  #pragma unroll
  for (int t = 0; t < TT; ++t)
    gate16[((size_t)(t*BB + b))*CC + c] = (f16)lif_hard(sums[t], v, 0.5f);
}

// ---------- output LIF: NHWC fp32 -> NCHW fp32, soft LIF * scale (LDS transpose) ----------
__global__ __launch_bounds__(256) void k_lif_out(const float* __restrict__ z, const float* __restrict__ scalep,
                                                 float* __restrict__ out) {
  __shared__ float tile[64][65];  // [p][c]
  const int p0 = blockIdx.x * 64, c0 = blockIdx.y * 64, b = blockIdx.z;
  const int l = threadIdx.x & 63, q = threadIdx.x >> 6;
  const float sc = scalep[0];
  float v[16];
  #pragma unroll
  for (int j = 0; j < 16; ++j) v[j] = 0.0f;
  for (int t = 0; t < TT; ++t) {
    __syncthreads();
    #pragma unroll
    for (int j = 0; j < 16; ++j) {
      int pi = q + j*4;
      tile[pi][l] = z[((size_t)(t*BB + b)*1024 + p0 + pi)*CC + c0 + l];
    }
    __syncthreads();
    #pragma unroll
    for (int j = 0; j < 16; ++j) {
      int ci = q + j*4;
      float s = lif_soft(tile[l][ci], v[j]) * sc;
      out[(((size_t)(t*BB + b))*CC + c0 + ci)*1024 + p0 + l] = s;
    }
  }
}

extern "C" void kernel_launch(void* const* d_in, const int* in_sizes, int n_in,
                              void* d_out, int out_size, void* d_ws, size_t ws_size,
                              hipStream_t stream) {
  const float* x      = (const float*)d_in[0];
  const float* r1_w1  = (const float*)d_in[1];
  const float* r1_bn1 = (const float*)d_in[2];
  const float* r1_dw  = (const float*)d_in[3];
  const float* r1_pw  = (const float*)d_in[4];
  const float* r1_bn2 = (const float*)d_in[5];
  const float* qkv_bn = (const float*)d_in[6];
  const float* r2_w1  = (const float*)d_in[7];
  const float* r2_bn1 = (const float*)d_in[8];
  const float* r2_dw  = (const float*)d_in[9];
  const float* r2_pw  = (const float*)d_in[10];
  const float* r2_bn2 = (const float*)d_in[11];
  const float* proj_bn= (const float*)d_in[12];
  const float* scale  = (const float*)d_in[13];

  float* ws = (float*)d_ws;
  const size_t SEG = 12582912;              // 50.3 MB in floats
  float* W0f = ws;                          // f16 region: xs -> p1a -> p2b
  float* W1  = ws + SEG;                    // 2 SEG fp32: t1 -> s16(f16) -> z
  float* W2f = ws + 3*SEG;                  // f16 region: p1b -> p2a
  float* W3  = ws + 4*SEG;                  // 2 SEG fp32: t2
  f16* xs  = (f16*)W0f;
  f16* p1a = (f16*)W0f;
  f16* p2b = (f16*)W0f;
  f16* p1b = (f16*)W2f;
  f16* p2a = (f16*)W2f;
  float* t1  = W1;
  f16*  s16  = (f16*)W1;                    // v-spikes (50.3 MB, after t1 dead)
  float* z   = W1;                          // gemm4 out (after s16 dead)
  float* t2  = W3;

  f16* wsp = (f16*)(ws + 6*SEG);            // disjoint param region (~6.2 MB)
  f16* w1a = wsp,              *w1b = wsp + 147456;
  f16* pwa = wsp + 294912,     *pwb = wsp + 589824;
  f16* q1a = wsp + 884736,     *q1b = wsp + 1032192;
  f16* qpa = wsp + 1179648,    *qpb = wsp + 1327104;
  f16* partial = wsp + 1474560;             // 64*4*16*384 = 1,572,864 f16
  f16* gate16  = wsp + 3047424;             // 64*384 = 24,576 f16
  float* par = (float*)(wsp + 3072000);     // 3840 floats of BN params
  float* s1 = par,        *o1 = par + 384;
  float* sA = par + 768,  *oA = par + 1536;
  float* s2 = par + 2304, *o2 = par + 2688;
  float* sB = par + 3072, *oB = par + 3456;

  const f16* nf = (const f16*)nullptr;
  f16* nf2 = (f16*)nullptr;

  k_prep<<<1, 768, 0, stream>>>(r1_bn1, r1_bn2, qkv_bn, r2_bn1, r2_bn2, proj_bn, par);
  k_wsplit<<<576, 256, 0, stream>>>(r1_w1, w1a, w1b, 147456);
  k_wsplit<<<1152, 256, 0, stream>>>(r1_pw, pwa, pwb, 294912);
  k_wsplit<<<576, 256, 0, stream>>>(r2_w1, q1a, q1b, 147456);
  k_wsplit<<<576, 256, 0, stream>>>(r2_pw, qpa, qpb, 147456);
  k_lif_in<<<dim3(16, 6, 16), 256, 0, stream>>>(x, xs);
  // repconv1
  k_gemm<2,0,0><<<dim3(3, 512), 256, 0, stream>>>(xs, nf, w1a, w1b, s1, o1, t1, t1, nf, nf2, nf2);
  k_dw<<<dim3(6, 32, 64), 256, 0, stream>>>(t1, r1_dw, o1, p1a, p1b);
  // qkv GEMM with fused LIF epilogue (t-grouped blocks): qk -> partial sums, v -> spikes
  k_gemm<3,1,0><<<dim3(6, 512), 256, 0, stream>>>(p1a, p1b, pwa, pwb, sA, oA,
                                                  (float*)nullptr, (float*)nullptr, nf, s16, partial);
  k_gate<<<24, 256, 0, stream>>>(partial, gate16);
  // repconv2 (gate applied inline on A-frags of gemm3)
  k_gemm<2,0,1><<<dim3(3, 512), 256, 0, stream>>>(s16, nf, q1a, q1b, s2, o2, t2, t2, gate16, nf2, nf2);
  k_dw<<<dim3(6, 32, 64), 256, 0, stream>>>(t2, r2_dw, o2, p2a, p2b);
  k_gemm<3,0,0><<<dim3(3, 512), 256, 0, stream>>>(p2a, p2b, qpa, qpb, sB, oB, z, z, nf, nf2, nf2);
  // output LIF * scale (NHWC -> NCHW)
  k_lif_out<<<dim3(16, 6, 16), 256, 0, stream>>>(z, scale, (float*)d_out);
}

// Round 10
// 519.110 us; speedup vs baseline: 1.3971x; 1.0485x over previous
//
#include <hip/hip_runtime.h>

typedef _Float16 f16;
typedef __attribute__((ext_vector_type(8))) _Float16 f16x8;
typedef __attribute__((ext_vector_type(4))) float f32x4;

#define TT 4
#define BB 16
#define CC 384

// ---------- LIF step helpers (mirror reference op order, no fma contraction) ----------
__device__ __forceinline__ float lif_soft(float x, float& v) {
  v = __fadd_rn(v, __fmul_rn(__fsub_rn(x, v), 0.5f));
  float s = (__fsub_rn(v, 1.0f) >= 0.0f) ? 1.0f : 0.0f;
  v = __fsub_rn(v, s);
  return s;
}
__device__ __forceinline__ float lif_hard(float x, float& v, float vth) {
  v = __fadd_rn(v, __fmul_rn(__fsub_rn(x, v), 0.5f));
  float s = (__fsub_rn(v, vth) >= 0.0f) ? 1.0f : 0.0f;
  if (s != 0.0f) v = 0.0f;
  return s;
}

// ---------- BN param folding (double precision) ----------
__global__ __launch_bounds__(768) void k_prep(const float* __restrict__ bn1,
                                              const float* __restrict__ bn2,
                                              const float* __restrict__ qkv,
                                              const float* __restrict__ rbn1,
                                              const float* __restrict__ rbn2,
                                              const float* __restrict__ proj,
                                              float* __restrict__ par) {
  int c = threadIdx.x;
  float* s1 = par;          float* o1 = par + 384;
  float* sA = par + 768;    float* oA = par + 1536;
  float* s2 = par + 2304;   float* o2 = par + 2688;
  float* sB = par + 3072;   float* oB = par + 3456;
  if (c < 384) {
    double a = (double)bn1[c] / sqrt((double)bn1[3*384+c] + 1e-5);
    s1[c] = (float)a;
    o1[c] = (float)((double)bn1[384+c] - (double)bn1[2*384+c]*a);
    double a2 = (double)rbn1[c] / sqrt((double)rbn1[3*384+c] + 1e-5);
    s2[c] = (float)a2;
    o2[c] = (float)((double)rbn1[384+c] - (double)rbn1[2*384+c]*a2);
    double a3 = (double)rbn2[c] / sqrt((double)rbn2[3*384+c] + 1e-5);
    double b3 = (double)rbn2[384+c] - (double)rbn2[2*384+c]*a3;
    double a4 = (double)proj[c] / sqrt((double)proj[3*384+c] + 1e-5);
    double b4 = (double)proj[384+c] - (double)proj[2*384+c]*a4;
    sB[c] = (float)(a3*a4);
    oB[c] = (float)(b3*a4 + b4);
  }
  if (c < 768) {
    double a5 = (double)bn2[c] / sqrt((double)bn2[3*768+c] + 1e-5);
    double b5 = (double)bn2[768+c] - (double)bn2[2*768+c]*a5;
    double a6 = (double)qkv[c] / sqrt((double)qkv[3*768+c] + 1e-5);
    double b6 = (double)qkv[768+c] - (double)qkv[2*768+c]*a6;
    sA[c] = (float)(a5*a6);
    oA[c] = (float)(b5*a6 + b6);
  }
}

// ---------- weight split: w = a + 2^-11 * b ----------
__global__ __launch_bounds__(256) void k_wsplit(const float* __restrict__ w,
                                                f16* __restrict__ wa, f16* __restrict__ wb, int n) {
  int i = blockIdx.x * 256 + threadIdx.x;
  if (i < n) {
    float x = w[i];
    f16 a = (f16)x;
    wa[i] = a;
    wb[i] = (f16)((x - (float)a) * 2048.0f);
  }
}

// ---------- input LIF: NCHW fp32 -> NHWC f16 spikes (LDS transpose) ----------
__global__ __launch_bounds__(256) void k_lif_in(const float* __restrict__ x, f16* __restrict__ xs) {
  __shared__ float tile[64][65];   // [c][p]
  const int p0 = blockIdx.x * 64, c0 = blockIdx.y * 64, b = blockIdx.z;
  const int l = threadIdx.x & 63, q = threadIdx.x >> 6;
  float v[16];
  #pragma unroll
  for (int j = 0; j < 16; ++j) v[j] = 0.0f;
  for (int t = 0; t < TT; ++t) {
    __syncthreads();
    #pragma unroll
    for (int j = 0; j < 16; ++j) {
      int ci = q + j*4;
      tile[ci][l] = x[(((size_t)(t*BB + b)*CC + c0 + ci) << 10) + p0 + l];
    }
    __syncthreads();
    #pragma unroll
    for (int j = 0; j < 16; ++j) {
      int pi = q + j*4;
      float s = lif_hard(tile[l][pi], v[j], 1.0f);
      xs[((size_t)(t*BB + b)*1024 + p0 + pi)*CC + c0 + l] = (f16)s;
    }
  }
}

// ---------- staging: global -> LDS, 64B rows, swizzle col ^= ((row>>1)&3)<<4 ----------
// EPI>=1 X-side uses t-grouped rows: gm = t*16384 + b*1024 + p0 + (row&31), t = row>>5.
template<int EPI>
__device__ __forceinline__ void stage_arrT(const f16* __restrict__ g, int m0, int b_, int p0,
                                           int k0, f16* dst, int lane, int i0, int i1, bool isX) {
  #pragma unroll
  for (int i = i0; i < i1; ++i) {
    int loff = i*1024 + lane*16;              // linear byte offset within 8 KB tile
    int row = loff >> 6, col = loff & 63;
    int scol = col ^ (((row >> 1) & 3) << 4); // inverse-swizzled SOURCE column
    int gm;
    if (EPI >= 1 && isX) gm = ((row >> 5) << 14) + (b_ << 10) + p0 + (row & 31);
    else                 gm = m0 + row;
    const char* src = (const char*)g + (size_t)gm*768 + (size_t)(k0*2) + scol;
    __builtin_amdgcn_global_load_lds((const __attribute__((address_space(1))) void*)src,
                                     (__attribute__((address_space(3))) void*)((char*)dst + i*1024),
                                     16, 0, 0);
  }
}

// fragment read with matching swizzle (row in [0,128), fq selects 16B k-slot)
__device__ __forceinline__ f16x8 fragld32(const f16* arr, int row, int fq) {
  int off = row*64 + ((fq*16) ^ (((row >> 1) & 3) << 4));
  return *(const f16x8*)((const char*)arr + off);
}

// ---------- split-f16 MFMA GEMM, 2-phase double-buffered (BK=32), XCD-chunked ----------
// NP: 2 or 3 MFMA passes. EPI: 0 = plain BN store; 1 = qkv fused epilogue (t-grouped
// blocks, in-LDS transpose, LIF over t; qk-half -> partial spike sums, v-half -> spikes);
// 2 = proj fused epilogue (transpose, soft LIF over t, x scale, NCHW write to out0;
// out1[0] = the scalar output scale). GATE: multiply A-frags by per-(tb,c) f16 gate.
template<int NP, int EPI, int GATE>
__global__ __launch_bounds__(256, 2) void k_gemm(const f16* __restrict__ X1, const f16* __restrict__ X2,
    const f16* __restrict__ Wa, const f16* __restrict__ Wb,
    const float* __restrict__ scale, const float* __restrict__ bias,
    float* __restrict__ out0, const float* __restrict__ out1,
    const f16* __restrict__ gatep, f16* __restrict__ sOut, f16* __restrict__ part) {
  constexpr int ARR = (NP == 3) ? 4 : 3;            // tiles per buffer
  __shared__ __align__(16) f16 lds[2*ARR*4096];     // 8 KB per tile (128 rows x 64 B)
  const int gx = gridDim.x;
  const int bid = blockIdx.y * gx + blockIdx.x;
  const int chunk = (gx * gridDim.y) >> 3;          // nwg % 8 == 0 for all our grids
  const int nb = (bid & 7) * chunk + (bid >> 3);    // chunked per-XCD, x fastest inside
  const int o0 = (nb % gx) * 128;
  const int mb = nb / gx;
  const int m0 = mb * 128;                          // EPI==0 row base
  const int b_ = mb >> 5, p0 = (mb & 31) << 5;      // EPI>=1 decode (b, p-slice)
  const int lane = threadIdx.x & 63, wid = threadIdx.x >> 6;
  const int wr = wid >> 1, wc = wid & 1;
  const int fr = lane & 15, fq = lane >> 4;
  f32x4 acc_h[4][4], acc_l[4][4];
  #pragma unroll
  for (int i = 0; i < 4; ++i)
    #pragma unroll
    for (int j = 0; j < 4; ++j) { acc_h[i][j] = (f32x4){0,0,0,0}; acc_l[i][j] = (f32x4){0,0,0,0}; }

  auto stage_all = [&](int buf, int k0) {
    f16* base = lds + buf*(ARR*4096);
    if (NP == 3) {
      if (wid == 0)      stage_arrT<EPI>(X1, m0, b_, p0, k0, base,          lane, 0, 8, true);
      else if (wid == 1) stage_arrT<EPI>(X2, m0, b_, p0, k0, base + 4096,   lane, 0, 8, true);
      else if (wid == 2) stage_arrT<EPI>(Wa, o0, b_, p0, k0, base + 2*4096, lane, 0, 8, false);
      else               stage_arrT<EPI>(Wb, o0, b_, p0, k0, base + 3*4096, lane, 0, 8, false);
    } else {
      if (wid == 0)      stage_arrT<EPI>(X1, m0, b_, p0, k0, base,          lane, 0, 4, true);
      else if (wid == 1) stage_arrT<EPI>(X1, m0, b_, p0, k0, base,          lane, 4, 8, true);
      else if (wid == 2) stage_arrT<EPI>(Wa, o0, b_, p0, k0, base + 4096,   lane, 0, 8, false);
      else               stage_arrT<EPI>(Wb, o0, b_, p0, k0, base + 2*4096, lane, 0, 8, false);
    }
  };

  // gate prefetch (GATE only): 16B of gate row for this block's (t,b), k-slot fq
  const char* gbase = nullptr;
  f16x8 g8{}, gn{};
  if constexpr (GATE) {
    gbase = (const char*)gatep + (size_t)(m0 >> 10)*768 + fq*16;
    g8 = *(const f16x8*)gbase;
  }

  // prologue: stage K-tile 0 into buf 0 (syncthreads drains vmcnt+lgkmcnt)
  stage_all(0, 0);
  __syncthreads();

  for (int it = 0; it < 12; ++it) {                 // K = 384 = 12 x 32
    const int cur = it & 1;
    if (it < 11) stage_all(cur ^ 1, (it + 1)*32);   // issue next tile FIRST (hides HBM latency)
    if constexpr (GATE) { if (it < 11) gn = *(const f16x8*)(gbase + (it + 1)*64); }
    const f16* bX1 = lds + cur*(ARR*4096);
    const f16* bW1 = (NP == 3) ? bX1 + 2*4096 : bX1 + 4096;
    const f16* bW2 = (NP == 3) ? bX1 + 3*4096 : bX1 + 2*4096;
    f16x8 a1[4], b1[4], b2[4];
    #pragma unroll
    for (int mi = 0; mi < 4; ++mi) a1[mi] = fragld32(bX1, wr*64 + mi*16 + fr, fq);
    if constexpr (GATE) {
      #pragma unroll
      for (int mi = 0; mi < 4; ++mi) a1[mi] = a1[mi] * g8;   // exact 0/1 * 0/1
    }
    #pragma unroll
    for (int oi = 0; oi < 4; ++oi) {
      b1[oi] = fragld32(bW1, wc*64 + oi*16 + fr, fq);
      b2[oi] = fragld32(bW2, wc*64 + oi*16 + fr, fq);
    }
    if (NP == 3) {
      const f16* bX2 = bX1 + 4096;
      f16x8 a2[4];
      #pragma unroll
      for (int mi = 0; mi < 4; ++mi) a2[mi] = fragld32(bX2, wr*64 + mi*16 + fr, fq);
      #pragma unroll
      for (int mi = 0; mi < 4; ++mi)
        #pragma unroll
        for (int oi = 0; oi < 4; ++oi) {
          acc_h[mi][oi] = __builtin_amdgcn_mfma_f32_16x16x32_f16(a1[mi], b1[oi], acc_h[mi][oi], 0, 0, 0);
          acc_l[mi][oi] = __builtin_amdgcn_mfma_f32_16x16x32_f16(a1[mi], b2[oi], acc_l[mi][oi], 0, 0, 0);
          acc_l[mi][oi] = __builtin_amdgcn_mfma_f32_16x16x32_f16(a2[mi], b1[oi], acc_l[mi][oi], 0, 0, 0);
        }
    } else {
      #pragma unroll
      for (int mi = 0; mi < 4; ++mi)
        #pragma unroll
        for (int oi = 0; oi < 4; ++oi) {
          acc_h[mi][oi] = __builtin_amdgcn_mfma_f32_16x16x32_f16(a1[mi], b1[oi], acc_h[mi][oi], 0, 0, 0);
          acc_l[mi][oi] = __builtin_amdgcn_mfma_f32_16x16x32_f16(a1[mi], b2[oi], acc_l[mi][oi], 0, 0, 0);
        }
    }
    __syncthreads();   // drains this wave's stage loads (vmcnt) + releases buf for overwrite
    if constexpr (GATE) { if (it < 11) g8 = gn; }
  }

  if constexpr (EPI == 0) {
    #pragma unroll
    for (int oi = 0; oi < 4; ++oi) {
      int o = o0 + wc*64 + oi*16 + fr;
      float sc = scale[o], bi = bias[o];
      #pragma unroll
      for (int mi = 0; mi < 4; ++mi) {
        f32x4 h = acc_h[mi][oi], lo2 = acc_l[mi][oi];
        #pragma unroll
        for (int r = 0; r < 4; ++r) {
          int m = m0 + wr*64 + mi*16 + fq*4 + r;
          float y = fmaf(0.00048828125f, lo2[r], h[r]);   // + 2^-11 * low
          out0[(size_t)m*384 + o] = fmaf(y, sc, bi);
        }
      }
    }
  } else {
    // fused epilogue: BN -> in-LDS transpose (XOR-swizzled cols) -> LIF over t
    float* T = (float*)lds;  // 128 x 128 fp32 = 64 KB (staging reads done: loop-final barrier)
    #pragma unroll
    for (int oi = 0; oi < 4; ++oi) {
      int ol = wc*64 + oi*16 + fr;
      float sc = scale[o0 + ol], bi = bias[o0 + ol];
      #pragma unroll
      for (int mi = 0; mi < 4; ++mi) {
        f32x4 h = acc_h[mi][oi], lo2 = acc_l[mi][oi];
        #pragma unroll
        for (int r = 0; r < 4; ++r) {
          int R = wr*64 + mi*16 + fq*4 + r;
          float y = fmaf(0.00048828125f, lo2[r], h[r]);
          T[R*128 + (ol ^ (R & 31))] = fmaf(y, sc, bi);
        }
      }
    }
    __syncthreads();
    const int tid = threadIdx.x;
    if constexpr (EPI == 1) {
      const int oc = tid & 127, ph = tid >> 7;
      if (o0 >= 384) {
        // v-half: spikes (exact 0/1) -> sOut[(t*16+b)*1024+p0+p][o0-384+oc]
        const int ocg = (o0 - 384) + oc;
        #pragma unroll
        for (int i = 0; i < 16; ++i) {
          int p = ph*16 + i;
          float v = 0.0f;
          #pragma unroll
          for (int t = 0; t < TT; ++t) {
            int R = t*32 + p;
            float s = lif_soft(T[R*128 + (oc ^ (R & 31))], v);
            sOut[((size_t)((t*16 + b_)*1024 + p0 + p))*384 + ocg] = (f16)s;
          }
        }
      } else {
        // qk-half: spike sums over this thread's 16 p (integer, f16-exact)
        float ps4[4] = {0,0,0,0};
        for (int i = 0; i < 16; ++i) {
          int p = ph*16 + i;
          float v = 0.0f;
          #pragma unroll
          for (int t = 0; t < TT; ++t) {
            int R = t*32 + p;
            ps4[t] += lif_soft(T[R*128 + (oc ^ (R & 31))], v);
          }
        }
        int slice = (p0 >> 4) + ph;   // 64 half-slices of 16 p
        #pragma unroll
        for (int t = 0; t < TT; ++t)
          part[(((size_t)slice*4 + t)*16 + b_)*384 + o0 + oc] = (f16)ps4[t];
      }
    } else {
      // EPI==2: soft LIF over t, x out1[0], direct NCHW fp32 write (lanes = consecutive p)
      const int p = tid & 31, cg = tid >> 5;   // 8 groups x 16 channels
      const float gsc = out1[0];
      #pragma unroll
      for (int j = 0; j < 16; ++j) {
        int c = cg*16 + j;
        float v = 0.0f;
        #pragma unroll
        for (int t = 0; t < TT; ++t) {
          int R = t*32 + p;
          float s = lif_soft(T[R*128 + (c ^ (R & 31))], v) * gsc;
          out0[(((size_t)(t*16 + b_)*384) + o0 + c)*1024 + p0 + p] = s;
        }
      }
    }
  }
}

// ---------- depthwise 3x3, NHWC, fp32 in -> split-f16 pair out, virtual pad pv[c] ----------
__global__ __launch_bounds__(256) void k_dw(const float* __restrict__ in, const float* __restrict__ wd,
                                            const float* __restrict__ pv,
                                            f16* __restrict__ outA, f16* __restrict__ outB) {
  const int ct = blockIdx.x, h = blockIdx.y, n = blockIdx.z;
  const int c = ct*64 + (threadIdx.x & 63);
  const int wq = threadIdx.x >> 6;
  float w9[9];
  #pragma unroll
  for (int i = 0; i < 9; ++i) w9[i] = wd[c*9 + i];
  const float pvc = pv[c];
  const float* base = in + (size_t)n*1024*CC;
  #pragma unroll
  for (int wi = 0; wi < 8; ++wi) {
    int w = wq*8 + wi;
    float acc = 0.0f;
    #pragma unroll
    for (int dh = -1; dh <= 1; ++dh)
      #pragma unroll
      for (int dw = -1; dw <= 1; ++dw) {
        int hh = h + dh, ww = w + dw;
        float vv = ((unsigned)hh < 32u && (unsigned)ww < 32u) ? base[(size_t)(hh*32 + ww)*CC + c] : pvc;
        acc = fmaf(w9[(dh+1)*3 + dw + 1], vv, acc);
      }
    f16 a = (f16)acc;
    size_t off = ((size_t)n*1024 + h*32 + w)*CC + c;
    outA[off] = a;
    outB[off] = (f16)((acc - (float)a) * 2048.0f);
  }
}

// ---------- gate: combine 64 partial half-slices + LIF(hard 0.5) -> f16 gate ----------
__global__ __launch_bounds__(256) void k_gate(const f16* __restrict__ partial, f16* __restrict__ gate16) {
  int g = blockIdx.x*256 + threadIdx.x;   // 6144 = 16*384
  int b = g / CC, c = g % CC;
  float sums[4];
  #pragma unroll
  for (int t = 0; t < TT; ++t) {
    float s = 0.0f;
    for (int ps = 0; ps < 64; ++ps) s += (float)partial[(((size_t)ps*4 + t)*BB + b)*CC + c];
    sums[t] = s;
  }
  float v = 0.0f;
  #pragma unroll
  for (int t = 0; t < TT; ++t)
    gate16[((size_t)(t*BB + b))*CC + c] = (f16)lif_hard(sums[t], v, 0.5f);
}

extern "C" void kernel_launch(void* const* d_in, const int* in_sizes, int n_in,
                              void* d_out, int out_size, void* d_ws, size_t ws_size,
                              hipStream_t stream) {
  const float* x      = (const float*)d_in[0];
  const float* r1_w1  = (const float*)d_in[1];
  const float* r1_bn1 = (const float*)d_in[2];
  const float* r1_dw  = (const float*)d_in[3];
  const float* r1_pw  = (const float*)d_in[4];
  const float* r1_bn2 = (const float*)d_in[5];
  const float* qkv_bn = (const float*)d_in[6];
  const float* r2_w1  = (const float*)d_in[7];
  const float* r2_bn1 = (const float*)d_in[8];
  const float* r2_dw  = (const float*)d_in[9];
  const float* r2_pw  = (const float*)d_in[10];
  const float* r2_bn2 = (const float*)d_in[11];
  const float* proj_bn= (const float*)d_in[12];
  const float* scale  = (const float*)d_in[13];

  float* ws = (float*)d_ws;
  const size_t SEG = 12582912;              // 50.3 MB in floats
  float* W0f = ws;                          // f16 region: xs -> p1a -> p2b
  float* W1  = ws + SEG;                    // 2 SEG fp32: t1 -> s16(f16)
  float* W2f = ws + 3*SEG;                  // f16 region: p1b -> p2a
  float* W3  = ws + 4*SEG;                  // 2 SEG fp32: t2
  f16* xs  = (f16*)W0f;
  f16* p1a = (f16*)W0f;
  f16* p2b = (f16*)W0f;
  f16* p1b = (f16*)W2f;
  f16* p2a = (f16*)W2f;
  float* t1  = W1;
  f16*  s16  = (f16*)W1;                    // v-spikes (50.3 MB, after t1 dead)
  float* t2  = W3;

  f16* wsp = (f16*)(ws + 6*SEG);            // disjoint param region (~6.2 MB)
  f16* w1a = wsp,              *w1b = wsp + 147456;
  f16* pwa = wsp + 294912,     *pwb = wsp + 589824;
  f16* q1a = wsp + 884736,     *q1b = wsp + 1032192;
  f16* qpa = wsp + 1179648,    *qpb = wsp + 1327104;
  f16* partial = wsp + 1474560;             // 64*4*16*384 = 1,572,864 f16
  f16* gate16  = wsp + 3047424;             // 64*384 = 24,576 f16
  float* par = (float*)(wsp + 3072000);     // 3840 floats of BN params
  float* s1 = par,        *o1 = par + 384;
  float* sA = par + 768,  *oA = par + 1536;
  float* s2 = par + 2304, *o2 = par + 2688;
  float* sB = par + 3072, *oB = par + 3456;

  const f16* nf = (const f16*)nullptr;
  f16* nf2 = (f16*)nullptr;

  k_prep<<<1, 768, 0, stream>>>(r1_bn1, r1_bn2, qkv_bn, r2_bn1, r2_bn2, proj_bn, par);
  k_wsplit<<<576, 256, 0, stream>>>(r1_w1, w1a, w1b, 147456);
  k_wsplit<<<1152, 256, 0, stream>>>(r1_pw, pwa, pwb, 294912);
  k_wsplit<<<576, 256, 0, stream>>>(r2_w1, q1a, q1b, 147456);
  k_wsplit<<<576, 256, 0, stream>>>(r2_pw, qpa, qpb, 147456);
  k_lif_in<<<dim3(16, 6, 16), 256, 0, stream>>>(x, xs);
  // repconv1
  k_gemm<2,0,0><<<dim3(3, 512), 256, 0, stream>>>(xs, nf, w1a, w1b, s1, o1, t1, nullptr, nf, nf2, nf2);
  k_dw<<<dim3(6, 32, 64), 256, 0, stream>>>(t1, r1_dw, o1, p1a, p1b);
  // qkv GEMM with fused LIF epilogue (t-grouped blocks): qk -> partial sums, v -> spikes
  k_gemm<3,1,0><<<dim3(6, 512), 256, 0, stream>>>(p1a, p1b, pwa, pwb, sA, oA,
                                                  nullptr, nullptr, nf, s16, partial);
  k_gate<<<24, 256, 0, stream>>>(partial, gate16);
  // repconv2 (gate applied inline on A-frags of gemm3)
  k_gemm<2,0,1><<<dim3(3, 512), 256, 0, stream>>>(s16, nf, q1a, q1b, s2, o2, t2, nullptr, gate16, nf2, nf2);
  k_dw<<<dim3(6, 32, 64), 256, 0, stream>>>(t2, r2_dw, o2, p2a, p2b);
  // proj GEMM with fused output LIF (t-grouped blocks), writes NCHW d_out directly
  k_gemm<3,2,0><<<dim3(3, 512), 256, 0, stream>>>(p2a, p2b, qpa, qpb, sB, oB,
                                                  (float*)d_out, scale, nf, nf2, nf2);
}

// Round 11
// 514.702 us; speedup vs baseline: 1.4091x; 1.0086x over previous
//
#include <hip/hip_runtime.h>

typedef _Float16 f16;
typedef __attribute__((ext_vector_type(8))) _Float16 f16x8;
typedef __attribute__((ext_vector_type(4))) _Float16 f16x4;
typedef __attribute__((ext_vector_type(4))) float f32x4;

#define TT 4
#define BB 16
#define CC 384

// epilogue transpose-buffer swizzle: spreads bank bit-4 via R's fq parity (R&4)
#define SWZ(R) ((((R) & 31)) ^ ((((R) & 4)) << 2))

// ---------- LIF step helpers (mirror reference op order, no fma contraction) ----------
__device__ __forceinline__ float lif_soft(float x, float& v) {
  v = __fadd_rn(v, __fmul_rn(__fsub_rn(x, v), 0.5f));
  float s = (__fsub_rn(v, 1.0f) >= 0.0f) ? 1.0f : 0.0f;
  v = __fsub_rn(v, s);
  return s;
}
__device__ __forceinline__ float lif_hard(float x, float& v, float vth) {
  v = __fadd_rn(v, __fmul_rn(__fsub_rn(x, v), 0.5f));
  float s = (__fsub_rn(v, vth) >= 0.0f) ? 1.0f : 0.0f;
  if (s != 0.0f) v = 0.0f;
  return s;
}

// ---------- BN param folding (double precision) ----------
__global__ __launch_bounds__(768) void k_prep(const float* __restrict__ bn1,
                                              const float* __restrict__ bn2,
                                              const float* __restrict__ qkv,
                                              const float* __restrict__ rbn1,
                                              const float* __restrict__ rbn2,
                                              const float* __restrict__ proj,
                                              float* __restrict__ par) {
  int c = threadIdx.x;
  float* s1 = par;          float* o1 = par + 384;
  float* sA = par + 768;    float* oA = par + 1536;
  float* s2 = par + 2304;   float* o2 = par + 2688;
  float* sB = par + 3072;   float* oB = par + 3456;
  if (c < 384) {
    double a = (double)bn1[c] / sqrt((double)bn1[3*384+c] + 1e-5);
    s1[c] = (float)a;
    o1[c] = (float)((double)bn1[384+c] - (double)bn1[2*384+c]*a);
    double a2 = (double)rbn1[c] / sqrt((double)rbn1[3*384+c] + 1e-5);
    s2[c] = (float)a2;
    o2[c] = (float)((double)rbn1[384+c] - (double)rbn1[2*384+c]*a2);
    double a3 = (double)rbn2[c] / sqrt((double)rbn2[3*384+c] + 1e-5);
    double b3 = (double)rbn2[384+c] - (double)rbn2[2*384+c]*a3;
    double a4 = (double)proj[c] / sqrt((double)proj[3*384+c] + 1e-5);
    double b4 = (double)proj[384+c] - (double)proj[2*384+c]*a4;
    sB[c] = (float)(a3*a4);
    oB[c] = (float)(b3*a4 + b4);
  }
  if (c < 768) {
    double a5 = (double)bn2[c] / sqrt((double)bn2[3*768+c] + 1e-5);
    double b5 = (double)bn2[768+c] - (double)bn2[2*768+c]*a5;
    double a6 = (double)qkv[c] / sqrt((double)qkv[3*768+c] + 1e-5);
    double b6 = (double)qkv[768+c] - (double)qkv[2*768+c]*a6;
    sA[c] = (float)(a5*a6);
    oA[c] = (float)(b5*a6 + b6);
  }
}

// ---------- weight split: w = a + 2^-11 * b ----------
__global__ __launch_bounds__(256) void k_wsplit(const float* __restrict__ w,
                                                f16* __restrict__ wa, f16* __restrict__ wb, int n) {
  int i = blockIdx.x * 256 + threadIdx.x;
  if (i < n) {
    float x = w[i];
    f16 a = (f16)x;
    wa[i] = a;
    wb[i] = (f16)((x - (float)a) * 2048.0f);
  }
}

// ---------- input LIF: NCHW fp32 -> NHWC f16 spikes (LDS transpose) ----------
__global__ __launch_bounds__(256) void k_lif_in(const float* __restrict__ x, f16* __restrict__ xs) {
  __shared__ float tile[64][65];   // [c][p]
  const int p0 = blockIdx.x * 64, c0 = blockIdx.y * 64, b = blockIdx.z;
  const int l = threadIdx.x & 63, q = threadIdx.x >> 6;
  float v[16];
  #pragma unroll
  for (int j = 0; j < 16; ++j) v[j] = 0.0f;
  for (int t = 0; t < TT; ++t) {
    __syncthreads();
    #pragma unroll
    for (int j = 0; j < 16; ++j) {
      int ci = q + j*4;
      tile[ci][l] = x[(((size_t)(t*BB + b)*CC + c0 + ci) << 10) + p0 + l];
    }
    __syncthreads();
    #pragma unroll
    for (int j = 0; j < 16; ++j) {
      int pi = q + j*4;
      float s = lif_hard(tile[l][pi], v[j], 1.0f);
      xs[((size_t)(t*BB + b)*1024 + p0 + pi)*CC + c0 + l] = (f16)s;
    }
  }
}

// ---------- staging: global -> LDS, 64B rows, swizzle col ^= ((row>>1)&3)<<4 ----------
// EPI>=1 X-side uses t-grouped rows: gm = t*16384 + b*1024 + p0 + (row&31), t = row>>5.
template<int EPI>
__device__ __forceinline__ void stage_arrT(const f16* __restrict__ g, int m0, int b_, int p0,
                                           int k0, f16* dst, int lane, int i0, int i1, bool isX) {
  #pragma unroll
  for (int i = i0; i < i1; ++i) {
    int loff = i*1024 + lane*16;              // linear byte offset within 8 KB tile
    int row = loff >> 6, col = loff & 63;
    int scol = col ^ (((row >> 1) & 3) << 4); // inverse-swizzled SOURCE column
    int gm;
    if (EPI >= 1 && isX) gm = ((row >> 5) << 14) + (b_ << 10) + p0 + (row & 31);
    else                 gm = m0 + row;
    const char* src = (const char*)g + (size_t)gm*768 + (size_t)(k0*2) + scol;
    __builtin_amdgcn_global_load_lds((const __attribute__((address_space(1))) void*)src,
                                     (__attribute__((address_space(3))) void*)((char*)dst + i*1024),
                                     16, 0, 0);
  }
}

// fragment read with matching swizzle (row in [0,128), fq selects 16B k-slot)
__device__ __forceinline__ f16x8 fragld32(const f16* arr, int row, int fq) {
  int off = row*64 + ((fq*16) ^ (((row >> 1) & 3) << 4));
  return *(const f16x8*)((const char*)arr + off);
}

// ---------- split-f16 MFMA GEMM, 2-phase double-buffered (BK=32), XCD-chunked ----------
// NP: 2 or 3 MFMA passes. EPI: 0 = plain BN store; 1 = qkv fused epilogue (t-grouped
// blocks, in-LDS transpose, LIF over t; qk-half -> partial spike sums, v-half -> spikes);
// 2 = proj fused epilogue (transpose, soft LIF over t, x scale, NCHW write to out0;
// out1[0] = the scalar output scale). GATE: multiply A-frags by per-(tb,c) f16 gate.
template<int NP, int EPI, int GATE>
__global__ __launch_bounds__(256, 2) void k_gemm(const f16* __restrict__ X1, const f16* __restrict__ X2,
    const f16* __restrict__ Wa, const f16* __restrict__ Wb,
    const float* __restrict__ scale, const float* __restrict__ bias,
    float* __restrict__ out0, const float* __restrict__ out1,
    const f16* __restrict__ gatep, f16* __restrict__ sOut, f16* __restrict__ part) {
  constexpr int ARR = (NP == 3) ? 4 : 3;            // tiles per buffer
  __shared__ __align__(16) f16 lds[2*ARR*4096];     // 8 KB per tile (128 rows x 64 B)
  const int gx = gridDim.x;
  const int bid = blockIdx.y * gx + blockIdx.x;
  const int chunk = (gx * gridDim.y) >> 3;          // nwg % 8 == 0 for all our grids
  const int nb = (bid & 7) * chunk + (bid >> 3);    // chunked per-XCD, x fastest inside
  const int o0 = (nb % gx) * 128;
  const int mb = nb / gx;
  const int m0 = mb * 128;                          // EPI==0 row base
  const int b_ = mb >> 5, p0 = (mb & 31) << 5;      // EPI>=1 decode (b, p-slice)
  const int lane = threadIdx.x & 63, wid = threadIdx.x >> 6;
  const int wr = wid >> 1, wc = wid & 1;
  const int fr = lane & 15, fq = lane >> 4;
  f32x4 acc_h[4][4], acc_l[4][4];
  #pragma unroll
  for (int i = 0; i < 4; ++i)
    #pragma unroll
    for (int j = 0; j < 4; ++j) { acc_h[i][j] = (f32x4){0,0,0,0}; acc_l[i][j] = (f32x4){0,0,0,0}; }

  auto stage_all = [&](int buf, int k0) {
    f16* base = lds + buf*(ARR*4096);
    if (NP == 3) {
      if (wid == 0)      stage_arrT<EPI>(X1, m0, b_, p0, k0, base,          lane, 0, 8, true);
      else if (wid == 1) stage_arrT<EPI>(X2, m0, b_, p0, k0, base + 4096,   lane, 0, 8, true);
      else if (wid == 2) stage_arrT<EPI>(Wa, o0, b_, p0, k0, base + 2*4096, lane, 0, 8, false);
      else               stage_arrT<EPI>(Wb, o0, b_, p0, k0, base + 3*4096, lane, 0, 8, false);
    } else {
      if (wid == 0)      stage_arrT<EPI>(X1, m0, b_, p0, k0, base,          lane, 0, 4, true);
      else if (wid == 1) stage_arrT<EPI>(X1, m0, b_, p0, k0, base,          lane, 4, 8, true);
      else if (wid == 2) stage_arrT<EPI>(Wa, o0, b_, p0, k0, base + 4096,   lane, 0, 8, false);
      else               stage_arrT<EPI>(Wb, o0, b_, p0, k0, base + 2*4096, lane, 0, 8, false);
    }
  };

  // gate prefetch (GATE only): 16B of gate row for this block's (t,b), k-slot fq
  const char* gbase = nullptr;
  f16x8 g8{}, gn{};
  if constexpr (GATE) {
    gbase = (const char*)gatep + (size_t)(m0 >> 10)*768 + fq*16;
    g8 = *(const f16x8*)gbase;
  }

  // prologue: stage K-tile 0 into buf 0 (syncthreads drains vmcnt+lgkmcnt)
  stage_all(0, 0);
  __syncthreads();

  for (int it = 0; it < 12; ++it) {                 // K = 384 = 12 x 32
    const int cur = it & 1;
    if (it < 11) stage_all(cur ^ 1, (it + 1)*32);   // issue next tile FIRST (hides HBM latency)
    if constexpr (GATE) { if (it < 11) gn = *(const f16x8*)(gbase + (it + 1)*64); }
    const f16* bX1 = lds + cur*(ARR*4096);
    const f16* bW1 = (NP == 3) ? bX1 + 2*4096 : bX1 + 4096;
    const f16* bW2 = (NP == 3) ? bX1 + 3*4096 : bX1 + 2*4096;
    f16x8 a1[4], b1[4], b2[4];
    #pragma unroll
    for (int mi = 0; mi < 4; ++mi) a1[mi] = fragld32(bX1, wr*64 + mi*16 + fr, fq);
    if constexpr (GATE) {
      #pragma unroll
      for (int mi = 0; mi < 4; ++mi) a1[mi] = a1[mi] * g8;   // exact 0/1 * 0/1
    }
    #pragma unroll
    for (int oi = 0; oi < 4; ++oi) {
      b1[oi] = fragld32(bW1, wc*64 + oi*16 + fr, fq);
      b2[oi] = fragld32(bW2, wc*64 + oi*16 + fr, fq);
    }
    if (NP == 3) {
      const f16* bX2 = bX1 + 4096;
      f16x8 a2[4];
      #pragma unroll
      for (int mi = 0; mi < 4; ++mi) a2[mi] = fragld32(bX2, wr*64 + mi*16 + fr, fq);
      #pragma unroll
      for (int mi = 0; mi < 4; ++mi)
        #pragma unroll
        for (int oi = 0; oi < 4; ++oi) {
          acc_h[mi][oi] = __builtin_amdgcn_mfma_f32_16x16x32_f16(a1[mi], b1[oi], acc_h[mi][oi], 0, 0, 0);
          acc_l[mi][oi] = __builtin_amdgcn_mfma_f32_16x16x32_f16(a1[mi], b2[oi], acc_l[mi][oi], 0, 0, 0);
          acc_l[mi][oi] = __builtin_amdgcn_mfma_f32_16x16x32_f16(a2[mi], b1[oi], acc_l[mi][oi], 0, 0, 0);
        }
    } else {
      #pragma unroll
      for (int mi = 0; mi < 4; ++mi)
        #pragma unroll
        for (int oi = 0; oi < 4; ++oi) {
          acc_h[mi][oi] = __builtin_amdgcn_mfma_f32_16x16x32_f16(a1[mi], b1[oi], acc_h[mi][oi], 0, 0, 0);
          acc_l[mi][oi] = __builtin_amdgcn_mfma_f32_16x16x32_f16(a1[mi], b2[oi], acc_l[mi][oi], 0, 0, 0);
        }
    }
    __syncthreads();   // drains this wave's stage loads (vmcnt) + releases buf for overwrite
    if constexpr (GATE) { if (it < 11) g8 = gn; }
  }

  if constexpr (EPI == 0) {
    #pragma unroll
    for (int oi = 0; oi < 4; ++oi) {
      int o = o0 + wc*64 + oi*16 + fr;
      float sc = scale[o], bi = bias[o];
      #pragma unroll
      for (int mi = 0; mi < 4; ++mi) {
        f32x4 h = acc_h[mi][oi], lo2 = acc_l[mi][oi];
        #pragma unroll
        for (int r = 0; r < 4; ++r) {
          int m = m0 + wr*64 + mi*16 + fq*4 + r;
          float y = fmaf(0.00048828125f, lo2[r], h[r]);   // + 2^-11 * low
          out0[(size_t)m*384 + o] = fmaf(y, sc, bi);
        }
      }
    }
  } else {
    // fused epilogue: BN -> in-LDS transpose (bank-spread swizzled cols) -> LIF over t
    float* T = (float*)lds;  // 128 x 128 fp32 = 64 KB (staging reads done: loop-final barrier)
    #pragma unroll
    for (int oi = 0; oi < 4; ++oi) {
      int ol = wc*64 + oi*16 + fr;
      float sc = scale[o0 + ol], bi = bias[o0 + ol];
      #pragma unroll
      for (int mi = 0; mi < 4; ++mi) {
        f32x4 h = acc_h[mi][oi], lo2 = acc_l[mi][oi];
        #pragma unroll
        for (int r = 0; r < 4; ++r) {
          int R = wr*64 + mi*16 + fq*4 + r;
          float y = fmaf(0.00048828125f, lo2[r], h[r]);
          T[R*128 + (ol ^ SWZ(R))] = fmaf(y, sc, bi);
        }
      }
    }
    __syncthreads();
    const int tid = threadIdx.x;
    if constexpr (EPI == 1) {
      const int oc = tid & 127, ph = tid >> 7;
      if (o0 >= 384) {
        // v-half: spikes (exact 0/1) -> sOut[(t*16+b)*1024+p0+p][o0-384+oc]
        const int ocg = (o0 - 384) + oc;
        #pragma unroll
        for (int i = 0; i < 16; ++i) {
          int p = ph*16 + i;
          float v = 0.0f;
          #pragma unroll
          for (int t = 0; t < TT; ++t) {
            int R = t*32 + p;
            float s = lif_soft(T[R*128 + (oc ^ SWZ(R))], v);
            sOut[((size_t)((t*16 + b_)*1024 + p0 + p))*384 + ocg] = (f16)s;
          }
        }
      } else {
        // qk-half: spike sums over this thread's 16 p (integer, f16-exact)
        float ps4[4] = {0,0,0,0};
        for (int i = 0; i < 16; ++i) {
          int p = ph*16 + i;
          float v = 0.0f;
          #pragma unroll
          for (int t = 0; t < TT; ++t) {
            int R = t*32 + p;
            ps4[t] += lif_soft(T[R*128 + (oc ^ SWZ(R))], v);
          }
        }
        int slice = (p0 >> 4) + ph;   // 64 half-slices of 16 p
        #pragma unroll
        for (int t = 0; t < TT; ++t)
          part[(((size_t)slice*4 + t)*16 + b_)*384 + o0 + oc] = (f16)ps4[t];
      }
    } else {
      // EPI==2: soft LIF over t, x out1[0], direct NCHW fp32 write (lanes = consecutive p)
      const int p = tid & 31, cg = tid >> 5;   // 8 groups x 16 channels
      const float gsc = out1[0];
      #pragma unroll
      for (int j = 0; j < 16; ++j) {
        int c = cg*16 + j;
        float v = 0.0f;
        #pragma unroll
        for (int t = 0; t < TT; ++t) {
          int R = t*32 + p;
          float s = lif_soft(T[R*128 + (c ^ SWZ(R))], v) * gsc;
          out0[(((size_t)(t*16 + b_)*384) + o0 + c)*1024 + p0 + p] = s;
        }
      }
    }
  }
}

// ---------- depthwise 3x3, NHWC, float4 channel-quads, fp32 in -> split-f16 out ----------
__global__ __launch_bounds__(256) void k_dw(const float* __restrict__ in, const float* __restrict__ wd,
                                            const float* __restrict__ pv,
                                            f16* __restrict__ outA, f16* __restrict__ outB) {
  const int ct = blockIdx.x, h = blockIdx.y, n = blockIdx.z;
  const int cq = threadIdx.x & 15, wg = threadIdx.x >> 4;   // 16 quads x 16 w-groups
  const int c0 = ct*64 + cq*4;
  const int w0 = wg*2;
  float w9[9][4];
  #pragma unroll
  for (int j = 0; j < 4; ++j)
    #pragma unroll
    for (int k = 0; k < 9; ++k) w9[k][j] = wd[(c0 + j)*9 + k];
  const float4 pv4 = *(const float4*)&pv[c0];
  const float* base = in + (size_t)n*1024*CC;
  float4 col[3][4];
  #pragma unroll
  for (int r = 0; r < 3; ++r)
    #pragma unroll
    for (int j = 0; j < 4; ++j) {
      int hh = h - 1 + r, ww = w0 - 1 + j;
      col[r][j] = ((unsigned)hh < 32u && (unsigned)ww < 32u)
                  ? *(const float4*)&base[(size_t)(hh*32 + ww)*CC + c0] : pv4;
    }
  #pragma unroll
  for (int wi = 0; wi < 2; ++wi) {
    float acc[4] = {0.f, 0.f, 0.f, 0.f};
    #pragma unroll
    for (int dh = 0; dh < 3; ++dh)
      #pragma unroll
      for (int dwj = 0; dwj < 3; ++dwj) {
        float4 vv = col[dh][wi + dwj];
        const float* wk = w9[dh*3 + dwj];
        acc[0] = fmaf(wk[0], vv.x, acc[0]);
        acc[1] = fmaf(wk[1], vv.y, acc[1]);
        acc[2] = fmaf(wk[2], vv.z, acc[2]);
        acc[3] = fmaf(wk[3], vv.w, acc[3]);
      }
    f16x4 a4, b4;
    #pragma unroll
    for (int j = 0; j < 4; ++j) {
      f16 a = (f16)acc[j];
      a4[j] = a;
      b4[j] = (f16)((acc[j] - (float)a) * 2048.0f);
    }
    size_t off = ((size_t)n*1024 + h*32 + w0 + wi)*CC + c0;
    *(f16x4*)&outA[off] = a4;
    *(f16x4*)&outB[off] = b4;
  }
}

// ---------- gate: combine 64 partial half-slices + LIF(hard 0.5) -> f16 gate ----------
__global__ __launch_bounds__(256) void k_gate(const f16* __restrict__ partial, f16* __restrict__ gate16) {
  int g = blockIdx.x*256 + threadIdx.x;   // 6144 = 16*384
  int b = g / CC, c = g % CC;
  float sums[4];
  #pragma unroll
  for (int t = 0; t < TT; ++t) {
    float s = 0.0f;
    for (int ps = 0; ps < 64; ++ps) s += (float)partial[(((size_t)ps*4 + t)*BB + b)*CC + c];
    sums[t] = s;
  }
  float v = 0.0f;
  #pragma unroll
  for (int t = 0; t < TT; ++t)
    gate16[((size_t)(t*BB + b))*CC + c] = (f16)lif_hard(sums[t], v, 0.5f);
}

extern "C" void kernel_launch(void* const* d_in, const int* in_sizes, int n_in,
                              void* d_out, int out_size, void* d_ws, size_t ws_size,
                              hipStream_t stream) {
  const float* x      = (const float*)d_in[0];
  const float* r1_w1  = (const float*)d_in[1];
  const float* r1_bn1 = (const float*)d_in[2];
  const float* r1_dw  = (const float*)d_in[3];
  const float* r1_pw  = (const float*)d_in[4];
  const float* r1_bn2 = (const float*)d_in[5];
  const float* qkv_bn = (const float*)d_in[6];
  const float* r2_w1  = (const float*)d_in[7];
  const float* r2_bn1 = (const float*)d_in[8];
  const float* r2_dw  = (const float*)d_in[9];
  const float* r2_pw  = (const float*)d_in[10];
  const float* r2_bn2 = (const float*)d_in[11];
  const float* proj_bn= (const float*)d_in[12];
  const float* scale  = (const float*)d_in[13];

  float* ws = (float*)d_ws;
  const size_t SEG = 12582912;              // 50.3 MB in floats
  float* W0f = ws;                          // f16 region: xs -> p1a -> p2b
  float* W1  = ws + SEG;                    // 2 SEG fp32: t1 -> s16(f16)
  float* W2f = ws + 3*SEG;                  // f16 region: p1b -> p2a
  float* W3  = ws + 4*SEG;                  // 2 SEG fp32: t2
  f16* xs  = (f16*)W0f;
  f16* p1a = (f16*)W0f;
  f16* p2b = (f16*)W0f;
  f16* p1b = (f16*)W2f;
  f16* p2a = (f16*)W2f;
  float* t1  = W1;
  f16*  s16  = (f16*)W1;                    // v-spikes (50.3 MB, after t1 dead)
  float* t2  = W3;

  f16* wsp = (f16*)(ws + 6*SEG);            // disjoint param region (~6.2 MB)
  f16* w1a = wsp,              *w1b = wsp + 147456;
  f16* pwa = wsp + 294912,     *pwb = wsp + 589824;
  f16* q1a = wsp + 884736,     *q1b = wsp + 1032192;
  f16* qpa = wsp + 1179648,    *qpb = wsp + 1327104;
  f16* partial = wsp + 1474560;             // 64*4*16*384 = 1,572,864 f16
  f16* gate16  = wsp + 3047424;             // 64*384 = 24,576 f16
  float* par = (float*)(wsp + 3072000);     // 3840 floats of BN params
  float* s1 = par,        *o1 = par + 384;
  float* sA = par + 768,  *oA = par + 1536;
  float* s2 = par + 2304, *o2 = par + 2688;
  float* sB = par + 3072, *oB = par + 3456;

  const f16* nf = (const f16*)nullptr;
  f16* nf2 = (f16*)nullptr;

  k_prep<<<1, 768, 0, stream>>>(r1_bn1, r1_bn2, qkv_bn, r2_bn1, r2_bn2, proj_bn, par);
  k_wsplit<<<576, 256, 0, stream>>>(r1_w1, w1a, w1b, 147456);
  k_wsplit<<<1152, 256, 0, stream>>>(r1_pw, pwa, pwb, 294912);
  k_wsplit<<<576, 256, 0, stream>>>(r2_w1, q1a, q1b, 147456);
  k_wsplit<<<576, 256, 0, stream>>>(r2_pw, qpa, qpb, 147456);
  k_lif_in<<<dim3(16, 6, 16), 256, 0, stream>>>(x, xs);
  // repconv1
  k_gemm<2,0,0><<<dim3(3, 512), 256, 0, stream>>>(xs, nf, w1a, w1b, s1, o1, t1, nullptr, nf, nf2, nf2);
  k_dw<<<dim3(6, 32, 64), 256, 0, stream>>>(t1, r1_dw, o1, p1a, p1b);
  // qkv GEMM with fused LIF epilogue (t-grouped blocks): qk -> partial sums, v -> spikes
  k_gemm<3,1,0><<<dim3(6, 512), 256, 0, stream>>>(p1a, p1b, pwa, pwb, sA, oA,
                                                  nullptr, nullptr, nf, s16, partial);
  k_gate<<<24, 256, 0, stream>>>(partial, gate16);
  // repconv2 (gate applied inline on A-frags of gemm3)
  k_gemm<2,0,1><<<dim3(3, 512), 256, 0, stream>>>(s16, nf, q1a, q1b, s2, o2, t2, nullptr, gate16, nf2, nf2);
  k_dw<<<dim3(6, 32, 64), 256, 0, stream>>>(t2, r2_dw, o2, p2a, p2b);
  // proj GEMM with fused output LIF (t-grouped blocks), writes NCHW d_out directly
  k_gemm<3,2,0><<<dim3(3, 512), 256, 0, stream>>>(p2a, p2b, qpa, qpb, sB, oB,
                                                  (float*)d_out, scale, nf, nf2, nf2);
}